// Round 2
// baseline (215.945 us; speedup 1.0000x reference)
//
#include <hip/hip_runtime.h>

typedef __attribute__((ext_vector_type(8))) short bf16x8;
typedef __attribute__((ext_vector_type(4))) float f32x4;

#define BATCH 2
#define SEQ 2048
#define DMODEL 768
#define NH 12
#define HD 64
#define M_TOK (BATCH * SEQ)   /* 4096 */
#define N_KQV (3 * DMODEL)    /* 2304 */

__device__ __forceinline__ unsigned short f2bf(float f) {
  unsigned int u = __float_as_uint(f);
  u += 0x7FFFu + ((u >> 16) & 1u);
  return (unsigned short)(u >> 16);
}

// ---------------- conversion kernels ----------------

__global__ void cvt_f32_bf16(const float* __restrict__ in,
                             unsigned short* __restrict__ out, int n4) {
  int i = blockIdx.x * blockDim.x + threadIdx.x;
  if (i >= n4) return;
  float4 v = reinterpret_cast<const float4*>(in)[i];
  unsigned long long p = (unsigned long long)f2bf(v.x)
                       | ((unsigned long long)f2bf(v.y) << 16)
                       | ((unsigned long long)f2bf(v.z) << 32)
                       | ((unsigned long long)f2bf(v.w) << 48);
  reinterpret_cast<unsigned long long*>(out)[i] = p;
}

// out[c][r] = bf16(in[r][c]); rows, cols divisible by 32
__global__ void transpose_cvt(const float* __restrict__ in,
                              unsigned short* __restrict__ out,
                              int rows, int cols) {
  __shared__ float tile[32][33];
  int c0 = blockIdx.x * 32, r0 = blockIdx.y * 32;
  for (int i = threadIdx.y; i < 32; i += 8)
    tile[i][threadIdx.x] = in[(size_t)(r0 + i) * cols + c0 + threadIdx.x];
  __syncthreads();
  for (int i = threadIdx.y; i < 32; i += 8)
    out[(size_t)(c0 + i) * rows + r0 + threadIdx.x] = f2bf(tile[threadIdx.x][i]);
}

// ---------------- GEMM: C[M,N] = A[M,K] @ BT[N,K]^T + bias ----------------
// MODE 0: epilogue splits kqv -> k/q/v buffers (q scaled by 0.125, v transposed)
// MODE 1: epilogue writes f32 out + bias
template <int MODE>
__global__ __launch_bounds__(256) void gemm_bt(
    const unsigned short* __restrict__ A,   // [M][K] bf16
    const unsigned short* __restrict__ BT,  // [N][K] bf16
    const float* __restrict__ bias,         // [N]
    int M, int N, int K,
    unsigned short* __restrict__ outK, unsigned short* __restrict__ outQ,
    unsigned short* __restrict__ outVT, float* __restrict__ outF) {
  __shared__ __align__(16) unsigned short lds_a[128][40];  // +8 pad, row stride 80B (16B mult)
  __shared__ __align__(16) unsigned short lds_b[128][40];
  const int tid = threadIdx.x;
  const int lane = tid & 63;
  const int w = tid >> 6;
  const int wm = w >> 1, wn = w & 1;       // 2x2 waves, 64x64 each
  const int l15 = lane & 15, lg = lane >> 4;
  const int m0 = blockIdx.y * 128, n0 = blockIdx.x * 128;

  f32x4 acc[4][4];
#pragma unroll
  for (int i = 0; i < 4; i++)
#pragma unroll
    for (int j = 0; j < 4; j++) acc[i][j] = (f32x4){0.f, 0.f, 0.f, 0.f};

  const int r1 = tid >> 2;           // staging row (0..63), +64 for 2nd chunk
  const int p1 = (tid & 3) * 8;      // k position within BK=32

  for (int k0 = 0; k0 < K; k0 += 32) {
    __syncthreads();
    *(bf16x8*)&lds_a[r1][p1]      = *(const bf16x8*)&A[(size_t)(m0 + r1) * K + k0 + p1];
    *(bf16x8*)&lds_a[r1 + 64][p1] = *(const bf16x8*)&A[(size_t)(m0 + r1 + 64) * K + k0 + p1];
    *(bf16x8*)&lds_b[r1][p1]      = *(const bf16x8*)&BT[(size_t)(n0 + r1) * K + k0 + p1];
    *(bf16x8*)&lds_b[r1 + 64][p1] = *(const bf16x8*)&BT[(size_t)(n0 + r1 + 64) * K + k0 + p1];
    __syncthreads();
    bf16x8 af[4], bfr[4];
#pragma unroll
    for (int mi = 0; mi < 4; mi++)
      af[mi] = *(const bf16x8*)&lds_a[wm * 64 + mi * 16 + l15][lg * 8];
#pragma unroll
    for (int ni = 0; ni < 4; ni++)
      bfr[ni] = *(const bf16x8*)&lds_b[wn * 64 + ni * 16 + l15][lg * 8];
#pragma unroll
    for (int mi = 0; mi < 4; mi++)
#pragma unroll
      for (int ni = 0; ni < 4; ni++)
        acc[mi][ni] = __builtin_amdgcn_mfma_f32_16x16x32_bf16(af[mi], bfr[ni], acc[mi][ni], 0, 0, 0);
  }

#pragma unroll
  for (int mi = 0; mi < 4; mi++) {
#pragma unroll
    for (int ni = 0; ni < 4; ni++) {
#pragma unroll
      for (int r = 0; r < 4; r++) {
        int row = m0 + wm * 64 + mi * 16 + lg * 4 + r;  // C/D: row=(lane>>4)*4+reg
        int col = n0 + wn * 64 + ni * 16 + l15;         // C/D: col=lane&15
        float v = acc[mi][ni][r] + bias[col];
        if (MODE == 0) {
          int chunk = col / DMODEL;          // 0=k, 1=q, 2=v (reference split order)
          int d = col - chunk * DMODEL;
          int h = d >> 6, di = d & 63;
          int bb = row >> 11, tok = row & 2047;
          int bh = bb * NH + h;
          if (chunk == 0)
            outK[((size_t)bh * SEQ + tok) * HD + di] = f2bf(v);
          else if (chunk == 1)
            outQ[((size_t)bh * SEQ + tok) * HD + di] = f2bf(v * 0.125f);  // 1/sqrt(64)
          else
            outVT[((size_t)bh * HD + di) * SEQ + tok] = f2bf(v);  // [B,H,hd,N]
        } else {
          outF[(size_t)row * N + col] = v;
        }
      }
    }
  }
}

// ---------------- flash attention: wave-independent, zero barriers ----------------
// grid: (SEQ/16, BATCH*NH), block 64 (1 wave = 16 q-rows)
// K/V fragments read directly from global (L2-resident); P via wave-private LDS.
__global__ __launch_bounds__(64) void attn_kernel(
    const unsigned short* __restrict__ qbuf,  // [BH][SEQ][HD], pre-scaled by 1/8
    const unsigned short* __restrict__ kbuf,  // [BH][SEQ][HD]
    const unsigned short* __restrict__ vT,    // [BH][HD][SEQ]
    unsigned short* __restrict__ sa) {        // [B][SEQ][DMODEL]
  __shared__ __align__(16) unsigned short p_lds[16][72];
  const int lane = threadIdx.x & 63;
  const int l15 = lane & 15, lg = lane >> 4;
  const int qsub = (int)gridDim.x - 1 - (int)blockIdx.x;  // reversed: longest first
  const int qt = qsub >> 2;        // 64-row tile index (for causal bound)
  const int w = qsub & 3;          // 16-row subtile within the 64-row tile
  const int bh = blockIdx.y;
  const int qrow0 = qt * 64 + w * 16;
  const size_t qk_base = (size_t)bh * SEQ * HD;
  const size_t v_base = (size_t)bh * HD * SEQ;

  // Q fragments: rows qrow0..qrow0+15, direct from global
  bf16x8 aq[2];
#pragma unroll
  for (int ss = 0; ss < 2; ss++)
    aq[ss] = *(const bf16x8*)&qbuf[qk_base + (size_t)(qrow0 + l15) * HD + ss * 32 + lg * 8];

  f32x4 o[4];
  float m_run[4], l_run[4];
#pragma unroll
  for (int i = 0; i < 4; i++) {
    o[i] = (f32x4){0.f, 0.f, 0.f, 0.f};
    m_run[i] = -1e30f;
    l_run[i] = 0.f;
  }

  for (int kt = 0; kt <= qt; ++kt) {
    const unsigned short* kb = &kbuf[qk_base + (size_t)kt * 64 * HD];
    const unsigned short* vb = &vT[v_base + (size_t)kt * 64];

    // prefetch V fragments early: independent of S, latency hides under softmax
    bf16x8 bv[2][4];
#pragma unroll
    for (int ks = 0; ks < 2; ks++)
#pragma unroll
      for (int ni = 0; ni < 4; ni++)
        bv[ks][ni] = *(const bf16x8*)&vb[(size_t)(ni * 16 + l15) * SEQ + ks * 32 + lg * 8];

    // S = Q @ K^T  (16 q-rows x 64 kcols)
    f32x4 s[4];
#pragma unroll
    for (int ni = 0; ni < 4; ni++) s[ni] = (f32x4){0.f, 0.f, 0.f, 0.f};
#pragma unroll
    for (int ss = 0; ss < 2; ss++)
#pragma unroll
      for (int ni = 0; ni < 4; ni++) {
        bf16x8 bk = *(const bf16x8*)&kb[(size_t)(ni * 16 + l15) * HD + ss * 32 + lg * 8];
        s[ni] = __builtin_amdgcn_mfma_f32_16x16x32_bf16(aq[ss], bk, s[ni], 0, 0, 0);
      }

    // causal mask on the diagonal tile + online softmax
    float sv[4][4];
    const bool diag = (kt == qt);
#pragma unroll
    for (int ni = 0; ni < 4; ni++)
#pragma unroll
      for (int r = 0; r < 4; r++) {
        float val = s[ni][r];
        if (diag) {
          int qloc = w * 16 + lg * 4 + r;   // row within 64-tile
          int kloc = ni * 16 + l15;         // col within 64-tile
          if (kloc > qloc) val = -1e30f;
        }
        sv[ni][r] = val;
      }
#pragma unroll
    for (int r = 0; r < 4; r++) {
      float mx = fmaxf(fmaxf(sv[0][r], sv[1][r]), fmaxf(sv[2][r], sv[3][r]));
#pragma unroll
      for (int msk = 1; msk < 16; msk <<= 1) mx = fmaxf(mx, __shfl_xor(mx, msk));
      float mnew = fmaxf(m_run[r], mx);
      float sc = __expf(m_run[r] - mnew);
      float rs = 0.f;
#pragma unroll
      for (int ni = 0; ni < 4; ni++) {
        float p = __expf(sv[ni][r] - mnew);
        sv[ni][r] = p;
        rs += p;
      }
#pragma unroll
      for (int msk = 1; msk < 16; msk <<= 1) rs += __shfl_xor(rs, msk);
      l_run[r] = l_run[r] * sc + rs;
      m_run[r] = mnew;
#pragma unroll
      for (int ni = 0; ni < 4; ni++) o[ni][r] *= sc;
    }

    // P -> wave-private LDS (bf16); within-wave ordering only, no barrier
#pragma unroll
    for (int ni = 0; ni < 4; ni++)
#pragma unroll
      for (int r = 0; r < 4; r++)
        p_lds[lg * 4 + r][ni * 16 + l15] = f2bf(sv[ni][r]);

    // O += P @ V
#pragma unroll
    for (int ks = 0; ks < 2; ks++) {
      bf16x8 ap = *(const bf16x8*)&p_lds[l15][ks * 32 + lg * 8];
#pragma unroll
      for (int ni = 0; ni < 4; ni++)
        o[ni] = __builtin_amdgcn_mfma_f32_16x16x32_bf16(ap, bv[ks][ni], o[ni], 0, 0, 0);
    }
  }

  const int bb = bh / NH, h = bh - bb * NH;
#pragma unroll
  for (int ni = 0; ni < 4; ni++)
#pragma unroll
    for (int r = 0; r < 4; r++) {
      int qg = qrow0 + lg * 4 + r;
      int d = ni * 16 + l15;
      float val = o[ni][r] / l_run[r];
      sa[((size_t)bb * SEQ + qg) * DMODEL + h * HD + d] = f2bf(val);
    }
}

// ---------------- launch ----------------

extern "C" void kernel_launch(void* const* d_in, const int* in_sizes, int n_in,
                              void* d_out, int out_size, void* d_ws, size_t ws_size,
                              hipStream_t stream) {
  const float* x     = (const float*)d_in[0];
  const float* Wkqv  = (const float*)d_in[1];
  const float* bkqv  = (const float*)d_in[2];
  const float* Wproj = (const float*)d_in[3];
  const float* bproj = (const float*)d_in[4];
  float* out = (float*)d_out;

  char* ws = (char*)d_ws;
  // workspace layout (bytes)
  unsigned short* x_bf   = (unsigned short*)(ws + 0);         // 4096*768*2   = 6291456
  unsigned short* wkqvT  = (unsigned short*)(ws + 6291456);   // 2304*768*2   = 3538944
  unsigned short* wprojT = (unsigned short*)(ws + 9830400);   // 768*768*2    = 1179648
  unsigned short* qb     = (unsigned short*)(ws + 11010048);  // 24*2048*64*2 = 6291456
  unsigned short* kb     = (unsigned short*)(ws + 17301504);
  unsigned short* vT     = (unsigned short*)(ws + 23592960);
  unsigned short* sa     = (unsigned short*)(ws + 29884416);  // total ~36.2 MB

  cvt_f32_bf16<<<(M_TOK * DMODEL / 4 + 255) / 256, 256, 0, stream>>>(x, x_bf, M_TOK * DMODEL / 4);
  transpose_cvt<<<dim3(N_KQV / 32, DMODEL / 32), dim3(32, 8), 0, stream>>>(Wkqv, wkqvT, DMODEL, N_KQV);
  transpose_cvt<<<dim3(DMODEL / 32, DMODEL / 32), dim3(32, 8), 0, stream>>>(Wproj, wprojT, DMODEL, DMODEL);

  gemm_bt<0><<<dim3(N_KQV / 128, M_TOK / 128), 256, 0, stream>>>(
      x_bf, wkqvT, bkqv, M_TOK, N_KQV, DMODEL, kb, qb, vT, nullptr);

  attn_kernel<<<dim3(SEQ / 16, BATCH * NH), 64, 0, stream>>>(qb, kb, vT, sa);

  gemm_bt<1><<<dim3(DMODEL / 128, M_TOK / 128), 256, 0, stream>>>(
      sa, wprojT, bproj, M_TOK, DMODEL, DMODEL, nullptr, nullptr, nullptr, out);
}

// Round 3
// 148.072 us; speedup vs baseline: 1.4584x; 1.4584x over previous
//
#include <hip/hip_runtime.h>

typedef __attribute__((ext_vector_type(8))) short bf16x8;
typedef __attribute__((ext_vector_type(4))) float f32x4;

#define BATCH 2
#define SEQ 2048
#define DMODEL 768
#define NH 12
#define HD 64
#define M_TOK (BATCH * SEQ)   /* 4096 */
#define N_KQV (3 * DMODEL)    /* 2304 */

__device__ __forceinline__ unsigned short f2bf(float f) {
  unsigned int u = __float_as_uint(f);
  u += 0x7FFFu + ((u >> 16) & 1u);
  return (unsigned short)(u >> 16);
}

// ---------------- conversion kernels ----------------

__global__ void cvt_f32_bf16(const float* __restrict__ in,
                             unsigned short* __restrict__ out, int n4) {
  int i = blockIdx.x * blockDim.x + threadIdx.x;
  if (i >= n4) return;
  float4 v = reinterpret_cast<const float4*>(in)[i];
  unsigned long long p = (unsigned long long)f2bf(v.x)
                       | ((unsigned long long)f2bf(v.y) << 16)
                       | ((unsigned long long)f2bf(v.z) << 32)
                       | ((unsigned long long)f2bf(v.w) << 48);
  reinterpret_cast<unsigned long long*>(out)[i] = p;
}

// out[c][r] = bf16(in[r][c]); rows, cols divisible by 32
__global__ void transpose_cvt(const float* __restrict__ in,
                              unsigned short* __restrict__ out,
                              int rows, int cols) {
  __shared__ float tile[32][33];
  int c0 = blockIdx.x * 32, r0 = blockIdx.y * 32;
  for (int i = threadIdx.y; i < 32; i += 8)
    tile[i][threadIdx.x] = in[(size_t)(r0 + i) * cols + c0 + threadIdx.x];
  __syncthreads();
  for (int i = threadIdx.y; i < 32; i += 8)
    out[(size_t)(c0 + i) * rows + r0 + threadIdx.x] = f2bf(tile[threadIdx.x][i]);
}

// ---------------- GEMM: C[M,N] = A[M,K] @ BT[N,K]^T + bias ----------------
template <int MODE>
__global__ __launch_bounds__(256) void gemm_bt(
    const unsigned short* __restrict__ A,   // [M][K] bf16
    const unsigned short* __restrict__ BT,  // [N][K] bf16
    const float* __restrict__ bias,         // [N]
    int M, int N, int K,
    unsigned short* __restrict__ outK, unsigned short* __restrict__ outQ,
    unsigned short* __restrict__ outVT, float* __restrict__ outF) {
  __shared__ __align__(16) unsigned short lds_a[128][40];
  __shared__ __align__(16) unsigned short lds_b[128][40];
  const int tid = threadIdx.x;
  const int lane = tid & 63;
  const int w = tid >> 6;
  const int wm = w >> 1, wn = w & 1;
  const int l15 = lane & 15, lg = lane >> 4;
  const int m0 = blockIdx.y * 128, n0 = blockIdx.x * 128;

  f32x4 acc[4][4];
#pragma unroll
  for (int i = 0; i < 4; i++)
#pragma unroll
    for (int j = 0; j < 4; j++) acc[i][j] = (f32x4){0.f, 0.f, 0.f, 0.f};

  const int r1 = tid >> 2;
  const int p1 = (tid & 3) * 8;

  for (int k0 = 0; k0 < K; k0 += 32) {
    __syncthreads();
    *(bf16x8*)&lds_a[r1][p1]      = *(const bf16x8*)&A[(size_t)(m0 + r1) * K + k0 + p1];
    *(bf16x8*)&lds_a[r1 + 64][p1] = *(const bf16x8*)&A[(size_t)(m0 + r1 + 64) * K + k0 + p1];
    *(bf16x8*)&lds_b[r1][p1]      = *(const bf16x8*)&BT[(size_t)(n0 + r1) * K + k0 + p1];
    *(bf16x8*)&lds_b[r1 + 64][p1] = *(const bf16x8*)&BT[(size_t)(n0 + r1 + 64) * K + k0 + p1];
    __syncthreads();
    bf16x8 af[4], bfr[4];
#pragma unroll
    for (int mi = 0; mi < 4; mi++)
      af[mi] = *(const bf16x8*)&lds_a[wm * 64 + mi * 16 + l15][lg * 8];
#pragma unroll
    for (int ni = 0; ni < 4; ni++)
      bfr[ni] = *(const bf16x8*)&lds_b[wn * 64 + ni * 16 + l15][lg * 8];
#pragma unroll
    for (int mi = 0; mi < 4; mi++)
#pragma unroll
      for (int ni = 0; ni < 4; ni++)
        acc[mi][ni] = __builtin_amdgcn_mfma_f32_16x16x32_bf16(af[mi], bfr[ni], acc[mi][ni], 0, 0, 0);
  }

#pragma unroll
  for (int mi = 0; mi < 4; mi++) {
#pragma unroll
    for (int ni = 0; ni < 4; ni++) {
#pragma unroll
      for (int r = 0; r < 4; r++) {
        int row = m0 + wm * 64 + mi * 16 + lg * 4 + r;
        int col = n0 + wn * 64 + ni * 16 + l15;
        float v = acc[mi][ni][r] + bias[col];
        if (MODE == 0) {
          int chunk = col / DMODEL;          // 0=k, 1=q, 2=v
          int d = col - chunk * DMODEL;
          int h = d >> 6, di = d & 63;
          int bb = row >> 11, tok = row & 2047;
          int bh = bb * NH + h;
          if (chunk == 0)
            outK[((size_t)bh * SEQ + tok) * HD + di] = f2bf(v);
          else if (chunk == 1)
            outQ[((size_t)bh * SEQ + tok) * HD + di] = f2bf(v * 0.125f);
          else
            outVT[((size_t)bh * HD + di) * SEQ + tok] = f2bf(v);
        } else {
          outF[(size_t)row * N + col] = v;
        }
      }
    }
  }
}

// ---------------- flash attention: balanced pairs + prefetch pipeline ----------------
// grid: (32, BATCH*NH), block 128 (2 waves x 16 q-rows = 32-row tile).
// Block j handles 32-row q-tiles j and 63-j sequentially: exactly 33 k-iters each.
// Per iter: prefetch next K/V tile to regs -> compute on LDS tile -> barrier ->
// ds_write -> barrier. Coalesced staging, latency hidden under compute.
__global__ __launch_bounds__(128) void attn_kernel(
    const unsigned short* __restrict__ qbuf,  // [BH][SEQ][HD], pre-scaled by 1/8
    const unsigned short* __restrict__ kbuf,  // [BH][SEQ][HD]
    const unsigned short* __restrict__ vT,    // [BH][HD][SEQ]
    unsigned short* __restrict__ sa) {        // [B][SEQ][DMODEL]
  __shared__ __align__(16) unsigned short k_lds[64][72];   // [kcol][d]
  __shared__ __align__(16) unsigned short v_lds[64][72];   // [d][kcol]
  __shared__ __align__(16) unsigned short p_lds[2][16][72];
  const int tid = threadIdx.x, lane = tid & 63, w = tid >> 6;
  const int l15 = lane & 15, lg = lane >> 4;
  const int j = blockIdx.x, bh = blockIdx.y;
  const size_t qk_base = (size_t)bh * SEQ * HD;
  const size_t v_base = (size_t)bh * HD * SEQ;
  const int bb = bh / NH, h = bh - bb * NH;

  // staging pattern: rows sr+8p (p=0..3), 16B chunk sc; fully coalesced
  const int sr = w * 32 + (lane >> 3);
  const int sc = (lane & 7) * 8;

  int t = j;                 // current q-tile (32 rows)
  int ktmax = t >> 1;        // inclusive last k-tile index
  const int tB = 63 - j;

  // prologue: stage k-tile 0
  {
    bf16x8 rk[4], rv[4];
#pragma unroll
    for (int p = 0; p < 4; p++) {
      rk[p] = *(const bf16x8*)&kbuf[qk_base + (size_t)(sr + 8 * p) * HD + sc];
      rv[p] = *(const bf16x8*)&vT[v_base + (size_t)(sr + 8 * p) * SEQ + sc];
    }
#pragma unroll
    for (int p = 0; p < 4; p++) {
      *(bf16x8*)&k_lds[sr + 8 * p][sc] = rk[p];
      *(bf16x8*)&v_lds[sr + 8 * p][sc] = rv[p];
    }
  }

  bf16x8 aq[2];
#pragma unroll
  for (int ss = 0; ss < 2; ss++)
    aq[ss] = *(const bf16x8*)&qbuf[qk_base + (size_t)(t * 32 + w * 16 + l15) * HD + ss * 32 + lg * 8];

  f32x4 o[4];
  float m_run[4], l_run[4];
#pragma unroll
  for (int i = 0; i < 4; i++) {
    o[i] = (f32x4){0.f, 0.f, 0.f, 0.f};
    m_run[i] = -1e30f;
    l_run[i] = 0.f;
  }

  __syncthreads();

  int kt = 0;
  for (int it = 0; it < 33; ++it) {
    // ---- prefetch next tile's K/V into registers (coalesced) ----
    const int nrow = (kt < ktmax) ? (kt + 1) * 64 : 0;  // bridge: next q-tile restarts at kt=0
    bf16x8 rk[4], rv[4];
#pragma unroll
    for (int p = 0; p < 4; p++) {
      rk[p] = *(const bf16x8*)&kbuf[qk_base + (size_t)(nrow + sr + 8 * p) * HD + sc];
      rv[p] = *(const bf16x8*)&vT[v_base + (size_t)(sr + 8 * p) * SEQ + nrow + sc];
    }

    // ---- compute on current LDS tile (t, kt) ----
    f32x4 s[4];
#pragma unroll
    for (int ni = 0; ni < 4; ni++) s[ni] = (f32x4){0.f, 0.f, 0.f, 0.f};
#pragma unroll
    for (int ss = 0; ss < 2; ss++)
#pragma unroll
      for (int ni = 0; ni < 4; ni++) {
        bf16x8 bk = *(const bf16x8*)&k_lds[ni * 16 + l15][ss * 32 + lg * 8];
        s[ni] = __builtin_amdgcn_mfma_f32_16x16x32_bf16(aq[ss], bk, s[ni], 0, 0, 0);
      }

    float sv[4][4];
    const bool diag = (kt == ktmax);
#pragma unroll
    for (int ni = 0; ni < 4; ni++)
#pragma unroll
      for (int r = 0; r < 4; r++) {
        float val = s[ni][r];
        if (diag) {
          int qloc = (t & 1) * 32 + w * 16 + lg * 4 + r;  // pos within 64-wide k band
          int kloc = ni * 16 + l15;
          if (kloc > qloc) val = -1e30f;
        }
        sv[ni][r] = val;
      }
#pragma unroll
    for (int r = 0; r < 4; r++) {
      float mx = fmaxf(fmaxf(sv[0][r], sv[1][r]), fmaxf(sv[2][r], sv[3][r]));
#pragma unroll
      for (int msk = 1; msk < 16; msk <<= 1) mx = fmaxf(mx, __shfl_xor(mx, msk));
      float mnew = fmaxf(m_run[r], mx);
      float sc2 = __expf(m_run[r] - mnew);
      float rs = 0.f;
#pragma unroll
      for (int ni = 0; ni < 4; ni++) {
        float p = __expf(sv[ni][r] - mnew);
        sv[ni][r] = p;
        rs += p;
      }
#pragma unroll
      for (int msk = 1; msk < 16; msk <<= 1) rs += __shfl_xor(rs, msk);
      l_run[r] = l_run[r] * sc2 + rs;
      m_run[r] = mnew;
#pragma unroll
      for (int ni = 0; ni < 4; ni++) o[ni][r] *= sc2;
    }

    // P -> wave-private LDS (bf16)
#pragma unroll
    for (int ni = 0; ni < 4; ni++)
#pragma unroll
      for (int r = 0; r < 4; r++)
        p_lds[w][lg * 4 + r][ni * 16 + l15] = f2bf(sv[ni][r]);

    // O += P @ V
#pragma unroll
    for (int ks = 0; ks < 2; ks++) {
      bf16x8 ap = *(const bf16x8*)&p_lds[w][l15][ks * 32 + lg * 8];
#pragma unroll
      for (int ni = 0; ni < 4; ni++) {
        bf16x8 bv = *(const bf16x8*)&v_lds[ni * 16 + l15][ks * 32 + lg * 8];
        o[ni] = __builtin_amdgcn_mfma_f32_16x16x32_bf16(ap, bv, o[ni], 0, 0, 0);
      }
    }

    // ---- tile finished? write output, switch to mirror tile ----
    if (kt == ktmax) {
#pragma unroll
      for (int ni = 0; ni < 4; ni++)
#pragma unroll
        for (int r = 0; r < 4; r++) {
          int qg = t * 32 + w * 16 + lg * 4 + r;
          int d = ni * 16 + l15;
          sa[((size_t)bb * SEQ + qg) * DMODEL + h * HD + d] = f2bf(o[ni][r] / l_run[r]);
        }
      if (t != tB) {
        t = tB;
        ktmax = tB >> 1;
        kt = 0;
#pragma unroll
        for (int ss = 0; ss < 2; ss++)
          aq[ss] = *(const bf16x8*)&qbuf[qk_base + (size_t)(t * 32 + w * 16 + l15) * HD + ss * 32 + lg * 8];
#pragma unroll
        for (int i = 0; i < 4; i++) {
          o[i] = (f32x4){0.f, 0.f, 0.f, 0.f};
          m_run[i] = -1e30f;
          l_run[i] = 0.f;
        }
      }
    } else {
      kt++;
    }

    // ---- stage prefetched tile: one WAR barrier, write, one visibility barrier ----
    __syncthreads();
#pragma unroll
    for (int p = 0; p < 4; p++) {
      *(bf16x8*)&k_lds[sr + 8 * p][sc] = rk[p];
      *(bf16x8*)&v_lds[sr + 8 * p][sc] = rv[p];
    }
    __syncthreads();
  }
}

// ---------------- launch ----------------

extern "C" void kernel_launch(void* const* d_in, const int* in_sizes, int n_in,
                              void* d_out, int out_size, void* d_ws, size_t ws_size,
                              hipStream_t stream) {
  const float* x     = (const float*)d_in[0];
  const float* Wkqv  = (const float*)d_in[1];
  const float* bkqv  = (const float*)d_in[2];
  const float* Wproj = (const float*)d_in[3];
  const float* bproj = (const float*)d_in[4];
  float* out = (float*)d_out;

  char* ws = (char*)d_ws;
  unsigned short* x_bf   = (unsigned short*)(ws + 0);
  unsigned short* wkqvT  = (unsigned short*)(ws + 6291456);
  unsigned short* wprojT = (unsigned short*)(ws + 9830400);
  unsigned short* qb     = (unsigned short*)(ws + 11010048);
  unsigned short* kb     = (unsigned short*)(ws + 17301504);
  unsigned short* vT     = (unsigned short*)(ws + 23592960);
  unsigned short* sa     = (unsigned short*)(ws + 29884416);

  cvt_f32_bf16<<<(M_TOK * DMODEL / 4 + 255) / 256, 256, 0, stream>>>(x, x_bf, M_TOK * DMODEL / 4);
  transpose_cvt<<<dim3(N_KQV / 32, DMODEL / 32), dim3(32, 8), 0, stream>>>(Wkqv, wkqvT, DMODEL, N_KQV);
  transpose_cvt<<<dim3(DMODEL / 32, DMODEL / 32), dim3(32, 8), 0, stream>>>(Wproj, wprojT, DMODEL, DMODEL);

  gemm_bt<0><<<dim3(N_KQV / 128, M_TOK / 128), 256, 0, stream>>>(
      x_bf, wkqvT, bkqv, M_TOK, N_KQV, DMODEL, kb, qb, vT, nullptr);

  attn_kernel<<<dim3(32, BATCH * NH), 128, 0, stream>>>(qb, kb, vT, sa);

  gemm_bt<1><<<dim3(DMODEL / 128, M_TOK / 128), 256, 0, stream>>>(
      sa, wprojT, bproj, M_TOK, DMODEL, DMODEL, nullptr, nullptr, nullptr, out);
}

// Round 4
// 127.709 us; speedup vs baseline: 1.6909x; 1.1594x over previous
//
#include <hip/hip_runtime.h>

typedef __attribute__((ext_vector_type(8))) short bf16x8;
typedef __attribute__((ext_vector_type(4))) float f32x4;

#define BATCH 2
#define SEQ 2048
#define DMODEL 768
#define NH 12
#define HD 64
#define M_TOK (BATCH * SEQ)   /* 4096 */
#define N_KQV (3 * DMODEL)    /* 2304 */

__device__ __forceinline__ unsigned short f2bf(float f) {
  unsigned int u = __float_as_uint(f);
  u += 0x7FFFu + ((u >> 16) & 1u);
  return (unsigned short)(u >> 16);
}

// ---------------- conversion kernels ----------------

__global__ void cvt_f32_bf16(const float* __restrict__ in,
                             unsigned short* __restrict__ out, int n4) {
  int i = blockIdx.x * blockDim.x + threadIdx.x;
  if (i >= n4) return;
  float4 v = reinterpret_cast<const float4*>(in)[i];
  unsigned long long p = (unsigned long long)f2bf(v.x)
                       | ((unsigned long long)f2bf(v.y) << 16)
                       | ((unsigned long long)f2bf(v.z) << 32)
                       | ((unsigned long long)f2bf(v.w) << 48);
  reinterpret_cast<unsigned long long*>(out)[i] = p;
}

// out[c][r] = bf16(in[r][c]); rows, cols divisible by 32
__global__ void transpose_cvt(const float* __restrict__ in,
                              unsigned short* __restrict__ out,
                              int rows, int cols) {
  __shared__ float tile[32][33];
  int c0 = blockIdx.x * 32, r0 = blockIdx.y * 32;
  for (int i = threadIdx.y; i < 32; i += 8)
    tile[i][threadIdx.x] = in[(size_t)(r0 + i) * cols + c0 + threadIdx.x];
  __syncthreads();
  for (int i = threadIdx.y; i < 32; i += 8)
    out[(size_t)(c0 + i) * rows + r0 + threadIdx.x] = f2bf(tile[threadIdx.x][i]);
}

// ---------------- GEMM: C[M,N] = A[M,K] @ BT[N,K]^T + bias ----------------
template <int MODE>
__global__ __launch_bounds__(256) void gemm_bt(
    const unsigned short* __restrict__ A,   // [M][K] bf16
    const unsigned short* __restrict__ BT,  // [N][K] bf16
    const float* __restrict__ bias,         // [N]
    int M, int N, int K,
    unsigned short* __restrict__ outK, unsigned short* __restrict__ outQ,
    unsigned short* __restrict__ outVT, float* __restrict__ outF) {
  __shared__ __align__(16) unsigned short lds_a[128][40];
  __shared__ __align__(16) unsigned short lds_b[128][40];
  const int tid = threadIdx.x;
  const int lane = tid & 63;
  const int w = tid >> 6;
  const int wm = w >> 1, wn = w & 1;
  const int l15 = lane & 15, lg = lane >> 4;
  const int m0 = blockIdx.y * 128, n0 = blockIdx.x * 128;

  f32x4 acc[4][4];
#pragma unroll
  for (int i = 0; i < 4; i++)
#pragma unroll
    for (int j = 0; j < 4; j++) acc[i][j] = (f32x4){0.f, 0.f, 0.f, 0.f};

  const int r1 = tid >> 2;
  const int p1 = (tid & 3) * 8;

  for (int k0 = 0; k0 < K; k0 += 32) {
    __syncthreads();
    *(bf16x8*)&lds_a[r1][p1]      = *(const bf16x8*)&A[(size_t)(m0 + r1) * K + k0 + p1];
    *(bf16x8*)&lds_a[r1 + 64][p1] = *(const bf16x8*)&A[(size_t)(m0 + r1 + 64) * K + k0 + p1];
    *(bf16x8*)&lds_b[r1][p1]      = *(const bf16x8*)&BT[(size_t)(n0 + r1) * K + k0 + p1];
    *(bf16x8*)&lds_b[r1 + 64][p1] = *(const bf16x8*)&BT[(size_t)(n0 + r1 + 64) * K + k0 + p1];
    __syncthreads();
    bf16x8 af[4], bfr[4];
#pragma unroll
    for (int mi = 0; mi < 4; mi++)
      af[mi] = *(const bf16x8*)&lds_a[wm * 64 + mi * 16 + l15][lg * 8];
#pragma unroll
    for (int ni = 0; ni < 4; ni++)
      bfr[ni] = *(const bf16x8*)&lds_b[wn * 64 + ni * 16 + l15][lg * 8];
#pragma unroll
    for (int mi = 0; mi < 4; mi++)
#pragma unroll
      for (int ni = 0; ni < 4; ni++)
        acc[mi][ni] = __builtin_amdgcn_mfma_f32_16x16x32_bf16(af[mi], bfr[ni], acc[mi][ni], 0, 0, 0);
  }

#pragma unroll
  for (int mi = 0; mi < 4; mi++) {
#pragma unroll
    for (int ni = 0; ni < 4; ni++) {
#pragma unroll
      for (int r = 0; r < 4; r++) {
        int row = m0 + wm * 64 + mi * 16 + lg * 4 + r;
        int col = n0 + wn * 64 + ni * 16 + l15;
        float v = acc[mi][ni][r] + bias[col];
        if (MODE == 0) {
          int chunk = col / DMODEL;          // 0=k, 1=q, 2=v
          int d = col - chunk * DMODEL;
          int h = d >> 6, di = d & 63;
          int bb = row >> 11, tok = row & 2047;
          int bh = bb * NH + h;
          if (chunk == 0)
            outK[((size_t)bh * SEQ + tok) * HD + di] = f2bf(v);
          else if (chunk == 1)
            outQ[((size_t)bh * SEQ + tok) * HD + di] = f2bf(v * 0.125f);
          else
            outVT[((size_t)bh * HD + di) * SEQ + tok] = f2bf(v);
        } else {
          outF[(size_t)row * N + col] = v;
        }
      }
    }
  }
}

// ---------------- flash attention ----------------
// grid: 768 blocks remapped XCD-affine (bh%8 == flat%8), block 128 (2 waves).
// Block handles mirrored 32-row q-tiles (j, 63-j): exactly 33 k-iters each.
// Softmax: fixed-shift (no running max), denominator via ones-column MFMA.
__global__ __launch_bounds__(128) void attn_kernel(
    const unsigned short* __restrict__ qbuf,  // [BH][SEQ][HD], pre-scaled by 1/8
    const unsigned short* __restrict__ kbuf,  // [BH][SEQ][HD]
    const unsigned short* __restrict__ vT,    // [BH][HD][SEQ]
    unsigned short* __restrict__ sa) {        // [B][SEQ][DMODEL]
  __shared__ __align__(16) unsigned short k_lds[64][72];   // [kcol][d]
  __shared__ __align__(16) unsigned short v_lds[64][72];   // [d][kcol]
  __shared__ __align__(16) unsigned short p_lds[2][16][72];
  const int tid = threadIdx.x, lane = tid & 63, w = tid >> 6;
  const int l15 = lane & 15, lg = lane >> 4;

  // XCD-affine remap: flat dispatch id % 8 == XCD; keep same-bh blocks on one XCD
  const int fid = (int)blockIdx.y * (int)gridDim.x + (int)blockIdx.x;  // 0..767
  const int slot = fid >> 3, xcd = fid & 7;
  const int bh = ((slot >> 5) << 3) + xcd;   // 3 heads per XCD
  const int j = slot & 31;

  const size_t qk_base = (size_t)bh * SEQ * HD;
  const size_t v_base = (size_t)bh * HD * SEQ;
  const int bb = bh / NH, h = bh - bb * NH;

  // staging pattern: rows sr+8p (p=0..3), 16B chunk sc; fully coalesced
  const int sr = w * 32 + (lane >> 3);
  const int sc = (lane & 7) * 8;

  int t = j;                 // current q-tile (32 rows)
  int ktmax = t >> 1;        // inclusive last k-tile index
  const int tB = 63 - j;

  bf16x8 ones;
#pragma unroll
  for (int i = 0; i < 8; i++) ones[i] = (short)0x3F80;  // bf16 1.0

  // prologue: stage k-tile 0
  {
    bf16x8 rk[4], rv[4];
#pragma unroll
    for (int p = 0; p < 4; p++) {
      rk[p] = *(const bf16x8*)&kbuf[qk_base + (size_t)(sr + 8 * p) * HD + sc];
      rv[p] = *(const bf16x8*)&vT[v_base + (size_t)(sr + 8 * p) * SEQ + sc];
    }
#pragma unroll
    for (int p = 0; p < 4; p++) {
      *(bf16x8*)&k_lds[sr + 8 * p][sc] = rk[p];
      *(bf16x8*)&v_lds[sr + 8 * p][sc] = rv[p];
    }
  }

  bf16x8 aq[2];
#pragma unroll
  for (int ss = 0; ss < 2; ss++)
    aq[ss] = *(const bf16x8*)&qbuf[qk_base + (size_t)(t * 32 + w * 16 + l15) * HD + ss * 32 + lg * 8];

  f32x4 o[4], lacc;
#pragma unroll
  for (int i = 0; i < 4; i++) o[i] = (f32x4){0.f, 0.f, 0.f, 0.f};
  lacc = (f32x4){0.f, 0.f, 0.f, 0.f};

  __syncthreads();

  int kt = 0;
  for (int it = 0; it < 33; ++it) {
    // ---- prefetch next tile's K/V into registers (coalesced) ----
    const int nrow = (kt < ktmax) ? (kt + 1) * 64 : 0;  // bridge: next q-tile restarts at kt=0
    bf16x8 rk[4], rv[4];
#pragma unroll
    for (int p = 0; p < 4; p++) {
      rk[p] = *(const bf16x8*)&kbuf[qk_base + (size_t)(nrow + sr + 8 * p) * HD + sc];
      rv[p] = *(const bf16x8*)&vT[v_base + (size_t)(sr + 8 * p) * SEQ + nrow + sc];
    }

    // ---- S = Q @ K^T on current LDS tile ----
    f32x4 s[4];
#pragma unroll
    for (int ni = 0; ni < 4; ni++) s[ni] = (f32x4){0.f, 0.f, 0.f, 0.f};
#pragma unroll
    for (int ss = 0; ss < 2; ss++)
#pragma unroll
      for (int ni = 0; ni < 4; ni++) {
        bf16x8 bk = *(const bf16x8*)&k_lds[ni * 16 + l15][ss * 32 + lg * 8];
        s[ni] = __builtin_amdgcn_mfma_f32_16x16x32_bf16(aq[ss], bk, s[ni], 0, 0, 0);
      }

    // ---- fixed-shift softmax: P = exp(S), masked entries -> 0 ----
    const bool diag = (kt == ktmax);
#pragma unroll
    for (int ni = 0; ni < 4; ni++)
#pragma unroll
      for (int r = 0; r < 4; r++) {
        float val = s[ni][r];
        if (diag) {
          int qloc = (t & 1) * 32 + w * 16 + lg * 4 + r;  // pos within 64-wide k band
          int kloc = ni * 16 + l15;
          if (kloc > qloc) val = -1e30f;
        }
        p_lds[w][lg * 4 + r][ni * 16 + l15] = f2bf(__expf(val));
      }

    // ---- O += P @ V ; denominator via ones-column MFMA ----
#pragma unroll
    for (int ks = 0; ks < 2; ks++) {
      bf16x8 ap = *(const bf16x8*)&p_lds[w][l15][ks * 32 + lg * 8];
      lacc = __builtin_amdgcn_mfma_f32_16x16x32_bf16(ap, ones, lacc, 0, 0, 0);
#pragma unroll
      for (int ni = 0; ni < 4; ni++) {
        bf16x8 bv = *(const bf16x8*)&v_lds[ni * 16 + l15][ks * 32 + lg * 8];
        o[ni] = __builtin_amdgcn_mfma_f32_16x16x32_bf16(ap, bv, o[ni], 0, 0, 0);
      }
    }

    // ---- tile finished? write output, switch to mirror tile ----
    if (kt == ktmax) {
#pragma unroll
      for (int ni = 0; ni < 4; ni++)
#pragma unroll
        for (int r = 0; r < 4; r++) {
          int qg = t * 32 + w * 16 + lg * 4 + r;
          int d = ni * 16 + l15;
          sa[((size_t)bb * SEQ + qg) * DMODEL + h * HD + d] = f2bf(o[ni][r] / lacc[r]);
        }
      if (t != tB) {
        t = tB;
        ktmax = tB >> 1;
        kt = 0;
#pragma unroll
        for (int ss = 0; ss < 2; ss++)
          aq[ss] = *(const bf16x8*)&qbuf[qk_base + (size_t)(t * 32 + w * 16 + l15) * HD + ss * 32 + lg * 8];
#pragma unroll
        for (int i = 0; i < 4; i++) o[i] = (f32x4){0.f, 0.f, 0.f, 0.f};
        lacc = (f32x4){0.f, 0.f, 0.f, 0.f};
      }
    } else {
      kt++;
    }

    // ---- stage prefetched tile ----
    __syncthreads();
#pragma unroll
    for (int p = 0; p < 4; p++) {
      *(bf16x8*)&k_lds[sr + 8 * p][sc] = rk[p];
      *(bf16x8*)&v_lds[sr + 8 * p][sc] = rv[p];
    }
    __syncthreads();
  }
}

// ---------------- launch ----------------

extern "C" void kernel_launch(void* const* d_in, const int* in_sizes, int n_in,
                              void* d_out, int out_size, void* d_ws, size_t ws_size,
                              hipStream_t stream) {
  const float* x     = (const float*)d_in[0];
  const float* Wkqv  = (const float*)d_in[1];
  const float* bkqv  = (const float*)d_in[2];
  const float* Wproj = (const float*)d_in[3];
  const float* bproj = (const float*)d_in[4];
  float* out = (float*)d_out;

  char* ws = (char*)d_ws;
  unsigned short* x_bf   = (unsigned short*)(ws + 0);
  unsigned short* wkqvT  = (unsigned short*)(ws + 6291456);
  unsigned short* wprojT = (unsigned short*)(ws + 9830400);
  unsigned short* qb     = (unsigned short*)(ws + 11010048);
  unsigned short* kb     = (unsigned short*)(ws + 17301504);
  unsigned short* vT     = (unsigned short*)(ws + 23592960);
  unsigned short* sa     = (unsigned short*)(ws + 29884416);

  cvt_f32_bf16<<<(M_TOK * DMODEL / 4 + 255) / 256, 256, 0, stream>>>(x, x_bf, M_TOK * DMODEL / 4);
  transpose_cvt<<<dim3(N_KQV / 32, DMODEL / 32), dim3(32, 8), 0, stream>>>(Wkqv, wkqvT, DMODEL, N_KQV);
  transpose_cvt<<<dim3(DMODEL / 32, DMODEL / 32), dim3(32, 8), 0, stream>>>(Wproj, wprojT, DMODEL, DMODEL);

  gemm_bt<0><<<dim3(N_KQV / 128, M_TOK / 128), 256, 0, stream>>>(
      x_bf, wkqvT, bkqv, M_TOK, N_KQV, DMODEL, kb, qb, vT, nullptr);

  attn_kernel<<<dim3(32, BATCH * NH), 128, 0, stream>>>(qb, kb, vT, sa);

  gemm_bt<1><<<dim3(DMODEL / 128, M_TOK / 128), 256, 0, stream>>>(
      sa, wprojT, bproj, M_TOK, DMODEL, DMODEL, nullptr, nullptr, nullptr, out);
}